// Round 7
// baseline (3155.630 us; speedup 1.0000x reference)
//
#include <hip/hip_runtime.h>

#define TT 512
#define BB 64
#define II 512
#define LL 1024
#define GROUPS 16
#define RPG 4            // batch rows per group
#define WPG 16           // WGs per group (64 cols each)
#define NWGS (GROUPS * WPG)

typedef __bf16 bf16x8 __attribute__((ext_vector_type(8)));
typedef float f32x4 __attribute__((ext_vector_type(4)));
typedef unsigned int u32x4 __attribute__((ext_vector_type(4)));

// ---------- workspace layout (bytes) ----------
// wsWi : Wi frag-ordered bf16 (xi_gemm)                          = 1 MiB
// wsWh2: Wh frag-ordered bf16 [16 w][4 n4][32 ks][64 l][8e]      = 2 MiB
// hbuf : ping-pong compact H  2 x [16 g][32 ks][4 kq][4 r][8e]   = 256 KiB
// flags: [16 g][64] uints — one per producer WAVE (w*4+wv)       = 4 KiB
#define WSWI_OFF 0u
#define WSWH_OFF (1u << 20)
#define HBUF_OFF (3u << 20)
#define FLAG_OFF ((3u << 20) + (1u << 18))

__device__ __forceinline__ unsigned short f2bf(float f) {
  unsigned int u = __builtin_bit_cast(unsigned int, f);
  u += 0x7fffu + ((u >> 16) & 1u);   // round-to-nearest-even (inputs finite)
  return (unsigned short)(u >> 16);
}

__device__ __forceinline__ bf16x8 ld_frag(const unsigned short* p) {
  return __builtin_bit_cast(bf16x8, *(const uint4*)p);
}

// ============================================================
// prep: frag-order Wi (xi_gemm), Wh2 (scan), compact h0; zero flags.
// ============================================================
__global__ __launch_bounds__(256) void prep_kernel(
    const float* __restrict__ h0, const float* __restrict__ Wi,
    const float* __restrict__ Wh, unsigned short* __restrict__ wsWi,
    unsigned short* __restrict__ wsWh2, unsigned short* __restrict__ hbuf,
    unsigned int* __restrict__ flags) {
  int idx = blockIdx.x * 256 + threadIdx.x;
  if (idx < GROUPS * 64) flags[idx] = 0u;
  const float* src;
  unsigned short* dst;
  if (idx < 65536) {                       // Wi slots (for xi_gemm)
    int ln = idx & 63, s = idx >> 6;
    int nsub = s & 7, s2 = s >> 3, ks = s2 & 15, bn = s2 >> 4;
    int n = bn * 128 + nsub * 16 + (ln & 15);
    int k = ks * 32 + (ln >> 4) * 8;
    src = Wi + (size_t)n * II + k;
    dst = wsWi + (size_t)idx * 8;
  } else if (idx < 196608) {               // Wh2 slots
    int o = idx - 65536;                   // [w][n4][ks][l]
    int l = o & 63, s = o >> 6;
    int ks = s & 31, s2 = s >> 5;
    int n4 = s2 & 3, w = s2 >> 2;
    int col = w * 64 + n4 * 16 + (l & 15);
    int k = ks * 32 + (l >> 4) * 8;
    src = Wh + (size_t)col * LL + k;
    dst = wsWh2 + (size_t)o * 8;
  } else if (idx < 204800) {               // h0 compact slots
    int o = idx - 196608;                  // o = ((g*32+ks)*4+kq)*4+r
    int r = o & 3, kq = (o >> 2) & 3, ks = (o >> 4) & 31, g = o >> 9;
    src = h0 + (size_t)(g * RPG + r) * LL + ks * 32 + kq * 8;
    dst = hbuf + (size_t)o * 8;
  } else {
    return;
  }
  float4 a0 = *(const float4*)src;
  float4 a1 = *(const float4*)(src + 4);
  uint4 p;
  p.x = f2bf(a0.x) | ((unsigned)f2bf(a0.y) << 16);
  p.y = f2bf(a0.z) | ((unsigned)f2bf(a0.w) << 16);
  p.z = f2bf(a1.x) | ((unsigned)f2bf(a1.y) << 16);
  p.w = f2bf(a1.z) | ((unsigned)f2bf(a1.w) << 16);
  *(uint4*)dst = p;
}

// ============================================================
// xi = x @ Wi^T + bi  -> d_out (reused as xi buffer) [unchanged]
// ============================================================
__global__ __launch_bounds__(256) void xi_gemm(
    const float* __restrict__ x, const float* __restrict__ bi,
    const unsigned short* __restrict__ wsWi, float* __restrict__ out) {
  __shared__ unsigned short As[8 * 64 * 8];
  __shared__ unsigned short Bs[8 * 64 * 8];
  const int tid = threadIdx.x;
  const int ln = tid & 63;
  const int wv = tid >> 6;
  const int wm = wv >> 1, wn = wv & 1;
  const int bn = blockIdx.x;
  const int Mbase = blockIdx.y * 128;
  const int Nbase = bn * 128;

  f32x4 acc[4][4] = {};

  for (int ks = 0; ks < 16; ++ks) {
    __syncthreads();
#pragma unroll
    for (int i = 0; i < 2; ++i) {
      int slot = tid + 256 * i;
      int msub = slot >> 6;
      int l2 = slot & 63;
      const float* src =
          x + (size_t)(Mbase + msub * 16 + (l2 & 15)) * II + ks * 32 + (l2 >> 4) * 8;
      float4 a0 = *(const float4*)src;
      float4 a1 = *(const float4*)(src + 4);
      uint4 p;
      p.x = f2bf(a0.x) | ((unsigned)f2bf(a0.y) << 16);
      p.y = f2bf(a0.z) | ((unsigned)f2bf(a0.w) << 16);
      p.z = f2bf(a1.x) | ((unsigned)f2bf(a1.y) << 16);
      p.w = f2bf(a1.z) | ((unsigned)f2bf(a1.w) << 16);
      *(uint4*)(As + slot * 8) = p;
      const uint4* bsrc = (const uint4*)(wsWi + (size_t)(bn * 16 + ks) * 4096) + slot;
      *(uint4*)(Bs + slot * 8) = *bsrc;
    }
    __syncthreads();
    bf16x8 af[4];
#pragma unroll
    for (int m = 0; m < 4; ++m)
      af[m] = ld_frag(As + ((wm * 4 + m) * 64 + ln) * 8);
#pragma unroll
    for (int n = 0; n < 4; ++n) {
      bf16x8 bf = ld_frag(Bs + ((wn * 4 + n) * 64 + ln) * 8);
#pragma unroll
      for (int m = 0; m < 4; ++m)
        acc[m][n] = __builtin_amdgcn_mfma_f32_16x16x32_bf16(af[m], bf, acc[m][n], 0, 0, 0);
    }
  }
#pragma unroll
  for (int n = 0; n < 4; ++n) {
    int col = Nbase + wn * 64 + n * 16 + (ln & 15);
    float bv = bi[col];
#pragma unroll
    for (int m = 0; m < 4; ++m) {
      int row0 = Mbase + wm * 64 + m * 16 + (ln >> 4) * 4;
#pragma unroll
      for (int r = 0; r < 4; ++r)
        out[(size_t)(row0 + r) * LL + col] = acc[m][n][r] + bv;
    }
  }
}

// ============================================================
// Batch-grouped persistent scan, wave-decoupled.
// 16 groups x 4 rows; 16 WGs/group (64 cols); 4 waves/WG (16 cols each).
// ZERO __syncthreads in the loop: per-WAVE flags (64/group, wait-all),
// A-frags gathered global->reg (sc1, 256B/instr), counted vmcnt overlap,
// all-64-lane epilogue, wave-local LDS pack (lgkmcnt only).
// ============================================================
__global__ __launch_bounds__(256) void scan_kernel(
    const unsigned short* __restrict__ wsWh2, float* __restrict__ out,
    unsigned short* __restrict__ hbuf, unsigned int* __restrict__ flags) {
  extern __shared__ char smem[];
  unsigned short* Bfrag = (unsigned short*)smem;             // 128 KiB [n4][ks][l][8e]
  unsigned short* pwall = (unsigned short*)(smem + 131072);  // 512 B pack area

  const int tid = threadIdx.x;
  const int ln = tid & 63;
  const int wv = tid >> 6;                 // 0..3 : 16-col subtile
  const int g = blockIdx.x >> 4;           // group
  const int w = blockIdx.x & 15;           // col-slice within group
  const int kq = ln >> 4;                  // quad = batch row this lane owns
  const int rdup = ln & 3;
  const int cc = ln & 15;                  // col within wave's 16
  const int ks_w = w * 2 + (wv >> 1);      // wave's compact-h ks
  const int kqg0 = (wv & 1) * 2;           // wave's first kq block
  unsigned short* pw = pwall + wv * 64;    // wave-local pack (64 shorts)

  { // load this WG's Wh slice (128 KiB) into LDS once
    const uint4* src = (const uint4*)(wsWh2 + (size_t)w * 65536);
    uint4* dst = (uint4*)Bfrag;
#pragma unroll
    for (int i = 0; i < 32; ++i) dst[tid + 256 * i] = src[tid + 256 * i];
  }
  __syncthreads();

  const unsigned int* fp = flags + g * 64 + ln;
  const unsigned short* Bb = Bfrag + wv * 16384;

  for (int t = 0; t < TT; ++t) {
    // ---- xi prefetch (plain cached; lands during poll/gather) ----
    float xv;
    const float* xp = out + (size_t)t * 65536 + (size_t)(g * RPG + kq) * LL +
                      w * 64 + wv * 16 + cc;
    asm volatile("global_load_dword %0, %1, off" : "=&v"(xv) : "v"(xp) : "memory");

    // ---- wait-all: 64 producer waves published step t-1 ----
    if (t > 0) {
      unsigned f;
      do {
        f = __hip_atomic_load(fp, __ATOMIC_RELAXED, __HIP_MEMORY_SCOPE_AGENT);
      } while (__all((int)f >= t) == 0);
    }
    __builtin_amdgcn_sched_barrier(0);

    // ---- A-frag gather: 32 x dwordx4 sc1, each instr = 256B coalesced ----
    const unsigned short* hcur = hbuf + (size_t)(t & 1) * 65536 + g * 4096;
    const unsigned short* ga = hcur + (kq * 4 + rdup) * 8;
    const unsigned short* gb = ga + 2048;
    u32x4 hv[32];
#pragma unroll
    for (int i = 0; i < 16; ++i)
      asm volatile("global_load_dwordx4 %0, %1, off offset:%2 sc1"
                   : "=&v"(hv[i]) : "v"(ga), "i"(i * 256) : "memory");
#pragma unroll
    for (int i = 0; i < 16; ++i)
      asm volatile("global_load_dwordx4 %0, %1, off offset:%2 sc1"
                   : "=&v"(hv[16 + i]) : "v"(gb), "i"(i * 256) : "memory");

    // ---- MFMA in 4 phases, counted vmcnt overlaps gather with compute ----
    f32x4 c0 = {}, c1 = {};
    bf16x8 bf[8];
#pragma unroll
    for (int p = 0; p < 4; ++p) {
#pragma unroll
      for (int j = 0; j < 8; ++j)
        bf[j] = ld_frag(Bb + ((p * 8 + j) * 64 + ln) * 8);
      if (p == 0) asm volatile("s_waitcnt vmcnt(24)" ::: "memory");
      else if (p == 1) asm volatile("s_waitcnt vmcnt(16)" ::: "memory");
      else if (p == 2) asm volatile("s_waitcnt vmcnt(8)" ::: "memory");
      else asm volatile("s_waitcnt vmcnt(0)" ::: "memory");
      __builtin_amdgcn_sched_barrier(0);
#pragma unroll
      for (int j = 0; j < 8; j += 2) {
        c0 = __builtin_amdgcn_mfma_f32_16x16x32_bf16(
            __builtin_bit_cast(bf16x8, hv[p * 8 + j]), bf[j], c0, 0, 0, 0);
        c1 = __builtin_amdgcn_mfma_f32_16x16x32_bf16(
            __builtin_bit_cast(bf16x8, hv[p * 8 + j + 1]), bf[j + 1], c1, 0, 0, 0);
      }
    }
    f32x4 s = c0 + c1;

    // ---- epilogue, all 64 lanes: lane owns (row kq, col cc) ----
    float hval = tanhf(s[kq] + xv);   // s[r] = batch row r in every quad
    out[(size_t)t * 65536 + (size_t)(g * RPG + kq) * LL + w * 64 + wv * 16 + cc] = hval;
    pw[(cc >> 3) * 32 + kq * 8 + (cc & 7)] = f2bf(hval);
    asm volatile("s_waitcnt lgkmcnt(0)" ::: "memory");
    __builtin_amdgcn_sched_barrier(0);

    // ---- wave's 128B compact-h run: 8 lanes x 16B sc1 ----
    unsigned short* hnext = hbuf + (size_t)((t + 1) & 1) * 65536 + g * 4096;
    if (ln < 8) {
      u32x4 pk = *(const u32x4*)(pw + ln * 8);
      unsigned short* dp = hnext + (ks_w * 16 + kqg0 * 4 + ln) * 8;
      asm volatile("global_store_dwordx4 %0, %1, off sc1"
                   :: "v"(dp), "v"(pk) : "memory");
    }
    asm volatile("s_waitcnt vmcnt(0)" ::: "memory");
    if (ln == 0)
      __hip_atomic_store(flags + g * 64 + w * 4 + wv, (unsigned)(t + 1),
                         __ATOMIC_RELAXED, __HIP_MEMORY_SCOPE_AGENT);
  }
}

extern "C" void kernel_launch(void* const* d_in, const int* in_sizes, int n_in,
                              void* d_out, int out_size, void* d_ws, size_t ws_size,
                              hipStream_t stream) {
  const float* x  = (const float*)d_in[0];
  const float* h0 = (const float*)d_in[1];
  const float* Wi = (const float*)d_in[2];
  const float* bi = (const float*)d_in[3];
  const float* Wh = (const float*)d_in[4];
  float* out = (float*)d_out;
  char* ws = (char*)d_ws;
  unsigned short* wsWi  = (unsigned short*)(ws + WSWI_OFF);
  unsigned short* wsWh2 = (unsigned short*)(ws + WSWH_OFF);
  unsigned short* hbuf  = (unsigned short*)(ws + HBUF_OFF);
  unsigned int* flags   = (unsigned int*)(ws + FLAG_OFF);

  prep_kernel<<<800, 256, 0, stream>>>(h0, Wi, Wh, wsWi, wsWh2, hbuf, flags);
  xi_gemm<<<dim3(8, 256), 256, 0, stream>>>(x, bi, wsWi, out);
  void* args[] = {(void*)&wsWh2, (void*)&out, (void*)&hbuf, (void*)&flags};
  (void)hipLaunchCooperativeKernel(reinterpret_cast<void*>(scan_kernel),
                                   dim3(NWGS), dim3(256), args, 131584, stream);
}

// Round 8
// 1926.803 us; speedup vs baseline: 1.6378x; 1.6378x over previous
//
#include <hip/hip_runtime.h>

#define TT 512
#define BB 64
#define II 512
#define LL 1024
#define GROUPS 16
#define RPG 4            // batch rows per group
#define WPG 16           // WGs per group (64 cols each)
#define NWGS (GROUPS * WPG)

typedef __bf16 bf16x8 __attribute__((ext_vector_type(8)));
typedef float f32x4 __attribute__((ext_vector_type(4)));
typedef unsigned int u32x4 __attribute__((ext_vector_type(4)));

// ---------- workspace layout (bytes) ----------
// wsWi : Wi frag-ordered bf16 (xi_gemm)                          = 1 MiB
// wsWh2: Wh frag-ordered bf16 [16 w][4 n4][32 ks][64 l][8e]      = 2 MiB
// hbuf : ping-pong compact H  2 x [16 g][32 ks][4 kq][4 r][8e]   = 256 KiB
// flags: [16 g][64] uints — one per producer WAVE (w*4+wv)       = 4 KiB
#define WSWI_OFF 0u
#define WSWH_OFF (1u << 20)
#define HBUF_OFF (3u << 20)
#define FLAG_OFF ((3u << 20) + (1u << 18))

__device__ __forceinline__ unsigned short f2bf(float f) {
  unsigned int u = __builtin_bit_cast(unsigned int, f);
  u += 0x7fffu + ((u >> 16) & 1u);   // round-to-nearest-even (inputs finite)
  return (unsigned short)(u >> 16);
}

__device__ __forceinline__ bf16x8 ld_frag(const unsigned short* p) {
  return __builtin_bit_cast(bf16x8, *(const uint4*)p);
}

// ============================================================
// prep: frag-order Wi (xi_gemm), Wh2 (scan), compact h0; zero flags.
// ============================================================
__global__ __launch_bounds__(256) void prep_kernel(
    const float* __restrict__ h0, const float* __restrict__ Wi,
    const float* __restrict__ Wh, unsigned short* __restrict__ wsWi,
    unsigned short* __restrict__ wsWh2, unsigned short* __restrict__ hbuf,
    unsigned int* __restrict__ flags) {
  int idx = blockIdx.x * 256 + threadIdx.x;
  if (idx < GROUPS * 64) flags[idx] = 0u;
  const float* src;
  unsigned short* dst;
  if (idx < 65536) {                       // Wi slots (for xi_gemm)
    int ln = idx & 63, s = idx >> 6;
    int nsub = s & 7, s2 = s >> 3, ks = s2 & 15, bn = s2 >> 4;
    int n = bn * 128 + nsub * 16 + (ln & 15);
    int k = ks * 32 + (ln >> 4) * 8;
    src = Wi + (size_t)n * II + k;
    dst = wsWi + (size_t)idx * 8;
  } else if (idx < 196608) {               // Wh2 slots
    int o = idx - 65536;                   // [w][n4][ks][l]
    int l = o & 63, s = o >> 6;
    int ks = s & 31, s2 = s >> 5;
    int n4 = s2 & 3, w = s2 >> 2;
    int col = w * 64 + n4 * 16 + (l & 15);
    int k = ks * 32 + (l >> 4) * 8;
    src = Wh + (size_t)col * LL + k;
    dst = wsWh2 + (size_t)o * 8;
  } else if (idx < 204800) {               // h0 compact slots
    int o = idx - 196608;                  // o = ((g*32+ks)*4+kq)*4+r
    int r = o & 3, kq = (o >> 2) & 3, ks = (o >> 4) & 31, g = o >> 9;
    src = h0 + (size_t)(g * RPG + r) * LL + ks * 32 + kq * 8;
    dst = hbuf + (size_t)o * 8;
  } else {
    return;
  }
  float4 a0 = *(const float4*)src;
  float4 a1 = *(const float4*)(src + 4);
  uint4 p;
  p.x = f2bf(a0.x) | ((unsigned)f2bf(a0.y) << 16);
  p.y = f2bf(a0.z) | ((unsigned)f2bf(a0.w) << 16);
  p.z = f2bf(a1.x) | ((unsigned)f2bf(a1.y) << 16);
  p.w = f2bf(a1.z) | ((unsigned)f2bf(a1.w) << 16);
  *(uint4*)dst = p;
}

// ============================================================
// xi = x @ Wi^T + bi  -> d_out (reused as xi buffer) [unchanged]
// ============================================================
__global__ __launch_bounds__(256) void xi_gemm(
    const float* __restrict__ x, const float* __restrict__ bi,
    const unsigned short* __restrict__ wsWi, float* __restrict__ out) {
  __shared__ unsigned short As[8 * 64 * 8];
  __shared__ unsigned short Bs[8 * 64 * 8];
  const int tid = threadIdx.x;
  const int ln = tid & 63;
  const int wv = tid >> 6;
  const int wm = wv >> 1, wn = wv & 1;
  const int bn = blockIdx.x;
  const int Mbase = blockIdx.y * 128;
  const int Nbase = bn * 128;

  f32x4 acc[4][4] = {};

  for (int ks = 0; ks < 16; ++ks) {
    __syncthreads();
#pragma unroll
    for (int i = 0; i < 2; ++i) {
      int slot = tid + 256 * i;
      int msub = slot >> 6;
      int l2 = slot & 63;
      const float* src =
          x + (size_t)(Mbase + msub * 16 + (l2 & 15)) * II + ks * 32 + (l2 >> 4) * 8;
      float4 a0 = *(const float4*)src;
      float4 a1 = *(const float4*)(src + 4);
      uint4 p;
      p.x = f2bf(a0.x) | ((unsigned)f2bf(a0.y) << 16);
      p.y = f2bf(a0.z) | ((unsigned)f2bf(a0.w) << 16);
      p.z = f2bf(a1.x) | ((unsigned)f2bf(a1.y) << 16);
      p.w = f2bf(a1.z) | ((unsigned)f2bf(a1.w) << 16);
      *(uint4*)(As + slot * 8) = p;
      const uint4* bsrc = (const uint4*)(wsWi + (size_t)(bn * 16 + ks) * 4096) + slot;
      *(uint4*)(Bs + slot * 8) = *bsrc;
    }
    __syncthreads();
    bf16x8 af[4];
#pragma unroll
    for (int m = 0; m < 4; ++m)
      af[m] = ld_frag(As + ((wm * 4 + m) * 64 + ln) * 8);
#pragma unroll
    for (int n = 0; n < 4; ++n) {
      bf16x8 bf = ld_frag(Bs + ((wn * 4 + n) * 64 + ln) * 8);
#pragma unroll
      for (int m = 0; m < 4; ++m)
        acc[m][n] = __builtin_amdgcn_mfma_f32_16x16x32_bf16(af[m], bf, acc[m][n], 0, 0, 0);
    }
  }
#pragma unroll
  for (int n = 0; n < 4; ++n) {
    int col = Nbase + wn * 64 + n * 16 + (ln & 15);
    float bv = bi[col];
#pragma unroll
    for (int m = 0; m < 4; ++m) {
      int row0 = Mbase + wm * 64 + m * 16 + (ln >> 4) * 4;
#pragma unroll
      for (int r = 0; r < 4; ++r)
        out[(size_t)(row0 + r) * LL + col] = acc[m][n][r] + bv;
    }
  }
}

// ============================================================
// Batch-grouped persistent scan — hybrid (r6 shared gather +
// r7 wave-local epilogue/publish).
// 16 groups x 4 rows; 16 WGs/group; 4 waves/WG (16 cols each).
// Per step: partial-order poll (2 flags/thread) -> shared 8 KB
// gather (2 x 16B/thread, sc1) -> hA double-buffer write ->
// ONE __syncthreads -> MFMA (B-frags in registers) -> all-lane
// epilogue -> per-wave 128 B h-run store + per-wave flag.
// ============================================================
__global__ __launch_bounds__(256, 1) void scan_kernel(
    const unsigned short* __restrict__ wsWh2, float* __restrict__ out,
    unsigned short* __restrict__ hbuf, unsigned int* __restrict__ flags) {
  __shared__ unsigned short hA[2][4096];      // 2 x 8 KiB compact H
  __shared__ unsigned short packb[4][64];     // per-wave pack, 128 B each

  const int tid = threadIdx.x;
  const int ln = tid & 63;
  const int wv = tid >> 6;                 // 0..3 : 16-col subtile
  const int g = blockIdx.x >> 4;           // group
  const int w = blockIdx.x & 15;           // col-slice within group
  const int kq = ln >> 4;                  // batch row this lane owns
  const int rdup = ln & 3;
  const int cc = ln & 15;                  // col within wave's 16
  const int ks_w = w * 2 + (wv >> 1);      // wave's compact-h ks slot
  const int half = wv & 1;                 // which 64-short half of the slot

  // ---- B-frags resident in registers for the whole scan (128 VGPR) ----
  bf16x8 Breg[32];
  {
    const unsigned short* bsrc = wsWh2 + (size_t)(w * 4 + wv) * 16384 + ln * 8;
#pragma unroll
    for (int ks = 0; ks < 32; ++ks)
      Breg[ks] = ld_frag(bsrc + ks * 512);
  }

  // ---- this thread's two gather chunks and their producer flags ----
  const int c0 = tid, c1 = tid + 256;
  const int ks0 = c0 >> 4, kq0 = (c0 >> 2) & 3;
  const int f0i = (ks0 >> 1) * 4 + (ks0 & 1) * 2 + (kq0 >> 1);
  const unsigned int* fpa = flags + g * 64 + f0i;
  const unsigned int* fpb = fpa + 32;      // chunk c1 = c0 + 256 -> ks + 16 -> +32

  for (int t = 0; t < TT; ++t) {
    // ---- xi prefetch (plain cached; lands during poll/gather) ----
    float xv;
    const float* xp = out + (size_t)t * 65536 + (size_t)(g * RPG + kq) * LL +
                      w * 64 + wv * 16 + cc;
    asm volatile("global_load_dword %0, %1, off" : "=&v"(xv) : "v"(xp) : "memory");

    // ---- partial-order wait: only this thread's 2 producers ----
    if (t > 0) {
      unsigned fa, fb;
      do {
        fa = __hip_atomic_load(fpa, __ATOMIC_RELAXED, __HIP_MEMORY_SCOPE_AGENT);
        fb = __hip_atomic_load(fpb, __ATOMIC_RELAXED, __HIP_MEMORY_SCOPE_AGENT);
      } while (__all((int)fa >= t && (int)fb >= t) == 0);
    }
    __builtin_amdgcn_sched_barrier(0);

    // ---- shared gather: 8 KB group state, 2 x 16B per thread, sc1 ----
    const unsigned short* hcur = hbuf + (size_t)(t & 1) * 65536 + g * 4096;
    u32x4 hv0, hv1;
    asm volatile("global_load_dwordx4 %0, %1, off sc1"
                 : "=&v"(hv0) : "v"(hcur + c0 * 8) : "memory");
    asm volatile("global_load_dwordx4 %0, %1, off sc1"
                 : "=&v"(hv1) : "v"(hcur + c1 * 8) : "memory");
    asm volatile("s_waitcnt vmcnt(0)" ::: "memory");
    __builtin_amdgcn_sched_barrier(0);
    unsigned short* hw = hA[t & 1];
    *(u32x4*)(hw + c0 * 8) = hv0;
    *(u32x4*)(hw + c1 * 8) = hv1;
    __syncthreads();                       // the ONE block barrier per step

    // ---- MFMA: K=1024, A from LDS (broadcast), B from registers ----
    f32x4 a0 = {}, a1 = {};
#pragma unroll
    for (int ks = 0; ks < 32; ks += 2) {
      bf16x8 A0 = ld_frag(hw + (ks * 16 + kq * 4 + rdup) * 8);
      bf16x8 A1 = ld_frag(hw + ((ks + 1) * 16 + kq * 4 + rdup) * 8);
      a0 = __builtin_amdgcn_mfma_f32_16x16x32_bf16(A0, Breg[ks], a0, 0, 0, 0);
      a1 = __builtin_amdgcn_mfma_f32_16x16x32_bf16(A1, Breg[ks + 1], a1, 0, 0, 0);
    }
    f32x4 s = a0 + a1;

    // ---- all-lane epilogue: lane owns (row kq, col cc) ----
    float hval = tanhf(s[kq] + xv);
    out[(size_t)t * 65536 + (size_t)(g * RPG + kq) * LL + w * 64 + wv * 16 + cc] =
        hval;
    packb[wv][(cc >> 3) * 32 + kq * 8 + (cc & 7)] = f2bf(hval);
    asm volatile("s_waitcnt lgkmcnt(0)" ::: "memory");
    __builtin_amdgcn_sched_barrier(0);

    // ---- wave's 128 B compact-h run: 8 lanes x 16B sc1 ----
    unsigned short* hnext = hbuf + (size_t)((t + 1) & 1) * 65536 + g * 4096;
    if (ln < 8) {
      u32x4 pk = *(const u32x4*)(&packb[wv][ln * 8]);
      unsigned short* dp = hnext + ks_w * 128 + half * 64 + ln * 8;
      asm volatile("global_store_dwordx4 %0, %1, off sc1"
                   :: "v"(dp), "v"(pk) : "memory");
    }
    asm volatile("s_waitcnt vmcnt(0)" ::: "memory");
    if (ln == 0)
      __hip_atomic_store(flags + g * 64 + w * 4 + wv, (unsigned)(t + 1),
                         __ATOMIC_RELAXED, __HIP_MEMORY_SCOPE_AGENT);
  }
}

extern "C" void kernel_launch(void* const* d_in, const int* in_sizes, int n_in,
                              void* d_out, int out_size, void* d_ws, size_t ws_size,
                              hipStream_t stream) {
  const float* x  = (const float*)d_in[0];
  const float* h0 = (const float*)d_in[1];
  const float* Wi = (const float*)d_in[2];
  const float* bi = (const float*)d_in[3];
  const float* Wh = (const float*)d_in[4];
  float* out = (float*)d_out;
  char* ws = (char*)d_ws;
  unsigned short* wsWi  = (unsigned short*)(ws + WSWI_OFF);
  unsigned short* wsWh2 = (unsigned short*)(ws + WSWH_OFF);
  unsigned short* hbuf  = (unsigned short*)(ws + HBUF_OFF);
  unsigned int* flags   = (unsigned int*)(ws + FLAG_OFF);

  prep_kernel<<<800, 256, 0, stream>>>(h0, Wi, Wh, wsWi, wsWh2, hbuf, flags);
  xi_gemm<<<dim3(8, 256), 256, 0, stream>>>(x, bi, wsWi, out);
  void* args[] = {(void*)&wsWh2, (void*)&out, (void*)&hbuf, (void*)&flags};
  (void)hipLaunchCooperativeKernel(reinterpret_cast<void*>(scan_kernel),
                                   dim3(NWGS), dim3(256), args, 0, stream);
}